// Round 4
// baseline (115.330 us; speedup 1.0000x reference)
//
#include <hip/hip_runtime.h>
#include <hip/hip_bf16.h>

// AdaptiveFourierPositionEncoding — round 4: occupancy 2->4 waves/SIMD.
// W fragments + band params live in LDS (conflict-free fragment-linear
// layout), cutting VGPRs to <=128 so 4 waves/SIMD fit. 4096 persistent
// waves, 4 contiguous 16-token tiles each, depth-1 register prefetch.

#define NTOK   (8 * 32768)
#define NTILE  (NTOK / 16)       // 16384
#define NBLK   1024
#define WPB    4
#define NWAVE  (NBLK * WPB)      // 4096
#define TPW    (NTILE / NWAVE)   // 4 tiles per wave

typedef short  bf16x8 __attribute__((ext_vector_type(8)));
typedef float  f32x4  __attribute__((ext_vector_type(4)));

static __device__ __forceinline__ short f2bf(float f) {
    __hip_bfloat16 h = __float2bfloat16(f);   // RNE
    return __builtin_bit_cast(short, h);
}

__global__ __launch_bounds__(256, 4) void afpe_r4(
    const float* __restrict__ x, const int* __restrict__ pos,
    const float* __restrict__ fb, const float* __restrict__ ph,
    const float* __restrict__ aw, const float* __restrict__ ab,
    float* __restrict__ out)
{
    // W fragments, fragment-linear: chunk(m,c) @ (m*4+c)*1024 + lane*16.
    __shared__ __align__(16) char wlds[16384];
    __shared__ float pfb[64], pph[64], pab[64];

    const int tid  = threadIdx.x;
    const int lane = tid & 63;
    const int q    = lane >> 4;     // k-group / D-row group
    const int tt   = lane & 15;     // token-in-tile / A-row

    // ---- one-time staging: W -> bf16 frags in LDS, params -> LDS ----
    #pragma unroll
    for (int g0 = 0; g0 < 4; ++g0) {
        const int g  = g0 * 256 + tid;          // granule 0..1023
        const int mc = g >> 6, l = g & 63;
        const int sm = mc >> 2, sc = mc & 3, sq = l >> 4, st = l & 15;
        const float* wp = aw + (size_t)(16 * sm + st) * 128 + sq * 8 + 32 * sc;
        const float4 w0 = *(const float4*)wp;
        const float4 w1 = *(const float4*)(wp + 4);
        bf16x8 a;
        a[0] = f2bf(w0.x); a[1] = f2bf(w0.y); a[2] = f2bf(w0.z); a[3] = f2bf(w0.w);
        a[4] = f2bf(w1.x); a[5] = f2bf(w1.y); a[6] = f2bf(w1.z); a[7] = f2bf(w1.w);
        *(bf16x8*)(wlds + mc * 1024 + l * 16) = a;
    }
    if (tid < 64) { pfb[tid] = fb[tid]; pph[tid] = ph[tid]; pab[tid] = ab[tid]; }
    __syncthreads();

    const int gw = blockIdx.x * WPB + (tid >> 6);   // 0..4095
    const int t0 = gw * TPW;                        // 4 contiguous tiles

    // depth-1 double buffer in registers
    float4 xa[8], xb[8];
    int    pa, pb;
    {
        const float* base = x + (size_t)t0 * 2048 + tt * 128 + q * 8;
        #pragma unroll
        for (int c = 0; c < 4; ++c) {
            xa[2 * c]     = *(const float4*)(base + 32 * c);
            xa[2 * c + 1] = *(const float4*)(base + 32 * c + 4);
        }
        pa = pos[t0 * 16 + tt];
    }

    #pragma unroll
    for (int it = 0; it < TPW; ++it) {
        const int tile = t0 + it;
        float4* cur = (it & 1) ? xb : xa;
        float4* nxt = (it & 1) ? xa : xb;

        // prefetch next tile
        if (it + 1 < TPW) {
            const float* base = x + (size_t)(tile + 1) * 2048 + tt * 128 + q * 8;
            #pragma unroll
            for (int c = 0; c < 4; ++c) {
                nxt[2 * c]     = *(const float4*)(base + 32 * c);
                nxt[2 * c + 1] = *(const float4*)(base + 32 * c + 4);
            }
            if (it & 1) pa = pos[(tile + 1) * 16 + tt];
            else        pb = pos[(tile + 1) * 16 + tt];
        }
        const int pcur = (it & 1) ? pb : pa;

        // logits: acc[m] reg r = logit[band 16m + 4q + r][token tt]
        f32x4 acc[4];
        #pragma unroll
        for (int m = 0; m < 4; ++m) {
            const float4 abv = *(const float4*)&pab[16 * m + 4 * q];
            acc[m][0] = abv.x; acc[m][1] = abv.y; acc[m][2] = abv.z; acc[m][3] = abv.w;
        }
        #pragma unroll
        for (int c = 0; c < 4; ++c) {
            const float4 b0 = cur[2 * c], b1 = cur[2 * c + 1];
            bf16x8 B;
            B[0] = f2bf(b0.x); B[1] = f2bf(b0.y); B[2] = f2bf(b0.z); B[3] = f2bf(b0.w);
            B[4] = f2bf(b1.x); B[5] = f2bf(b1.y); B[6] = f2bf(b1.z); B[7] = f2bf(b1.w);
            #pragma unroll
            for (int m = 0; m < 4; ++m) {
                const bf16x8 A = *(const bf16x8*)(wlds + (m * 4 + c) * 1024 + lane * 16);
                acc[m] = __builtin_amdgcn_mfma_f32_16x16x32_bf16(A, B, acc[m], 0, 0, 0);
            }
        }

        // softmax over 64 bands of token tt (partners: lanes tt+16k)
        float e[4][4];
        float s = 0.f;
        #pragma unroll
        for (int m = 0; m < 4; ++m) {
            #pragma unroll
            for (int r = 0; r < 4; ++r) { e[m][r] = __expf(acc[m][r]); s += e[m][r]; }
        }
        s += __shfl_xor(s, 16, 64);
        s += __shfl_xor(s, 32, 64);
        const float rinv = 1.0f / s;

        // per-chunk trig + epilogue + store (keeps temps transient)
        const float pf = (float)pcur;
        float* ob = out + (size_t)(tile * 16 + tt) * 128 + q * 8;
        #pragma unroll
        for (int c = 0; c < 4; ++c) {
            const float4 fq4 = *(const float4*)&pfb[16 * c + 4 * q];
            const float4 ph4 = *(const float4*)&pph[16 * c + 4 * q];
            const float fq[4] = {fq4.x, fq4.y, fq4.z, fq4.w};
            const float pq[4] = {ph4.x, ph4.y, ph4.z, ph4.w};
            float sa[4], ca[4];
            #pragma unroll
            for (int r = 0; r < 4; ++r) {
                float ang = pf * fq[r];
                ang = ang + pq[r];
                double td = (double)ang * 0.15915494309189535;  // 1/(2*pi)
                td -= floor(td);
                const float rev = (float)td;
                const float at  = e[c][r] * rinv;
                sa[r] = __builtin_amdgcn_sinf(rev) * at;
                ca[r] = __builtin_amdgcn_cosf(rev) * at;
            }
            const float4 xv0 = cur[2 * c], xv1 = cur[2 * c + 1];
            float4 o0, o1;
            o0.x = xv0.x + sa[0]; o0.y = xv0.y + ca[0];
            o0.z = xv0.z + sa[1]; o0.w = xv0.w + ca[1];
            o1.x = xv1.x + sa[2]; o1.y = xv1.y + ca[2];
            o1.z = xv1.z + sa[3]; o1.w = xv1.w + ca[3];
            *(float4*)(ob + 32 * c)     = o0;
            *(float4*)(ob + 32 * c + 4) = o1;
        }
    }
}

extern "C" void kernel_launch(void* const* d_in, const int* in_sizes, int n_in,
                              void* d_out, int out_size, void* d_ws, size_t ws_size,
                              hipStream_t stream) {
    const float* x   = (const float*)d_in[0];
    const int*   pos = (const int*)d_in[1];
    const float* fb  = (const float*)d_in[2];
    const float* ph  = (const float*)d_in[3];
    const float* aw  = (const float*)d_in[4];
    const float* ab  = (const float*)d_in[5];
    float* out = (float*)d_out;

    // 1024 blocks x 4 waves = 4096 waves -> 4 waves/SIMD resident (VGPR<=128),
    // 4 contiguous tiles (64 tokens) per wave.
    afpe_r4<<<NBLK, 256, 0, stream>>>(x, pos, fb, ph, aw, ab, out);
}